// Round 11
// baseline (470.679 us; speedup 1.0000x reference)
//
#include <hip/hip_runtime.h>
#include <hip/hip_bf16.h>
#include <stdint.h>

typedef int v4i __attribute__((ext_vector_type(4)));

#define GM 4096
#define GN 16384
#define GK 4096
#define BM 256
#define BN 256
#define BK 64         // i8 bytes per K-step
#define NT (GK / BK)  // 64 K-tiles

// ---------------- per-row dynamic quantization -> fragment-ordered Xq2 ----------------
// Xq2[tm][kt][f][lane][16B]: lane l holds row tm*256 + f*16 + (l&15),
// k = kt*64 + (l>>4)*16 .. +16.  (identical geometry to Wt2)
__global__ __launch_bounds__(256) void quant_rows(
    const float* __restrict__ x, int8_t* __restrict__ xq2,
    float* __restrict__ xs, int K) {
  const int row = blockIdx.x;
  const int t = threadIdx.x;
  const float4* src = (const float4*)(x + (size_t)row * K) + t * 4;
  float4 v[4];
  float m = 0.f;
#pragma unroll
  for (int i = 0; i < 4; ++i) {
    v[i] = src[i];
    m = fmaxf(m, fmaxf(fmaxf(fabsf(v[i].x), fabsf(v[i].y)),
                       fmaxf(fabsf(v[i].z), fabsf(v[i].w))));
  }
#pragma unroll
  for (int off = 1; off < 64; off <<= 1)
    m = fmaxf(m, __shfl_xor(m, off, 64));
  __shared__ float wmax[4];
  if ((t & 63) == 0) wmax[t >> 6] = m;
  __syncthreads();
  const float gm = fmaxf(fmaxf(wmax[0], wmax[1]), fmaxf(wmax[2], wmax[3]));
  const float scale = (gm + 1e-5f) / 127.0f;  // == ref x_scales
  if (t == 0) xs[row] = scale;
  unsigned packed[4];
#pragma unroll
  for (int i = 0; i < 4; ++i) {
    float fv[4] = {v[i].x, v[i].y, v[i].z, v[i].w};
    unsigned p = 0;
#pragma unroll
    for (int j = 0; j < 4; ++j) {
      int q = (int)rintf(fv[j] / scale);  // RNE, matches np.round
      q = max(-128, min(127, q));
      p |= (unsigned)(q & 0xff) << (8 * j);
    }
    packed[i] = p;
  }
  // thread t owns the 16B chunk at k = t*16: kt = t>>2, kg = t&3
  const int tm = row >> 8, f = (row >> 4) & 15, fr = row & 15;
  const int kt = t >> 2, kg = t & 3;
  int8_t* dst =
      xq2 + ((((size_t)(tm * 64 + kt) * 16 + f) * 64) + fr + 16 * kg) * 16;
  *(int4*)dst =
      make_int4((int)packed[0], (int)packed[1], (int)packed[2], (int)packed[3]);
}

// ------- W int32 [K][N] -> Wt2 int8 in MFMA-fragment order -------
// Wt2[tn][kt][f][lane][16B]: lane l holds col n = tn*256 + f*16 + (l&15),
// k = kt*64 + (l>>4)*16 .. +16.  One fragment = 1 KB contiguous.
__global__ __launch_bounds__(256) void transpose_pack(
    const int* __restrict__ W32, int8_t* __restrict__ Wt2, int K, int N) {
  __shared__ __align__(16) int8_t tile[64][80];
  const int t = threadIdx.x;
  const int n0 = blockIdx.x * 64;
  const int k0 = blockIdx.y * 64;
  const int ln = t & 63;
  const int wv = t >> 6;
#pragma unroll
  for (int it = 0; it < 16; ++it) {
    const int kk = wv * 16 + it;
    tile[ln][kk] = (int8_t)W32[(size_t)(k0 + kk) * N + n0 + ln];
  }
  __syncthreads();
  const int lane = ln;
  const int4 v = *(const int4*)&tile[wv * 16 + (lane & 15)][(lane >> 4) * 16];
  const int tn = n0 >> 8;
  const int kt = k0 >> 6;
  const int f = ((n0 >> 4) & 15) + wv;
  *(int4*)(Wt2 + (((size_t)(tn * 64 + kt) * 16 + f) * 64 + lane) * 16) = v;
}

// ---- int8 GEMM: NO LDS, NO barriers. Both operands stream global->VGPR in ----
// ---- fragment order; self-paced waves; counted vmcnt(12), never drained.   ----
__global__ __launch_bounds__(512, 1) void gemm_i8(
    const int8_t* __restrict__ Xq2, const int8_t* __restrict__ Wt2,
    const float* __restrict__ xs, const float* __restrict__ wsc,
    const float* __restrict__ bias, float* __restrict__ C) {
  const int t = threadIdx.x;
  const int lane = t & 63;
  const int w = t >> 6;
  const int wr = w >> 2;  // 0..1 (M half: 128 rows)
  const int wc = w & 3;   // 0..3 (N quarter: 64 cols)
  const int fr = lane & 15;
  const int kg = lane >> 4;

  // bijective XCD swizzle: 1024 blocks = 8 XCD x (16 M x 8 N) rectangles
  const int bid = blockIdx.x;
  const int xcd = bid & 7;
  const int q = bid >> 3;
  const int tm = q & 15;
  const int tn = xcd * 8 + (q >> 4);
  const size_t rowA0 = (size_t)tm * BM;
  const size_t rowB0 = (size_t)tn * BN;

  // per-wave fragment bases (1 KB per fragment, 16 KB per K-tile panel)
  const int8_t* aq = Xq2 + (size_t)tm * 1048576 + wr * 8192 + (size_t)lane * 16;
  const int8_t* bq = Wt2 + (size_t)tn * 1048576 + wc * 4096 + (size_t)lane * 16;

  v4i acc[8][4] = {};
  v4i a[2][8], b[2][4];

#define LD(dst, ptr)                                        \
  asm volatile("global_load_dwordx4 %0, %1, off"            \
               : "=v"(dst)                                  \
               : "v"(ptr)                                   \
               : "memory")

#define LOAD_A_LO(T, S)                                     \
  {                                                         \
    const int8_t* p = aq + (size_t)(T)*16384;               \
    LD(a[S][0], p);                                         \
    LD(a[S][1], p + 1024);                                  \
    LD(a[S][2], p + 2048);                                  \
    LD(a[S][3], p + 3072);                                  \
  }
#define LOAD_A_HI(T, S)                                     \
  {                                                         \
    const int8_t* p = aq + (size_t)(T)*16384;               \
    LD(a[S][4], p + 4096);                                  \
    LD(a[S][5], p + 5120);                                  \
    LD(a[S][6], p + 6144);                                  \
    LD(a[S][7], p + 7168);                                  \
  }
#define LOAD_B(T, S)                                        \
  {                                                         \
    const int8_t* p = bq + (size_t)(T)*16384;               \
    LD(b[S][0], p);                                         \
    LD(b[S][1], p + 1024);                                  \
    LD(b[S][2], p + 2048);                                  \
    LD(b[S][3], p + 3072);                                  \
  }

#define SB __builtin_amdgcn_sched_barrier(0)

#define BODY(T, S)                                                            \
  {                                                                           \
    /* gate: batch T landed (batch T+1's 12 loads still in flight) */         \
    asm volatile("s_waitcnt vmcnt(12)" ::: "memory");                         \
    SB;                                                                       \
    __builtin_amdgcn_s_setprio(1);                                            \
    _Pragma("unroll") for (int mi = 0; mi < 4; ++mi)                          \
        _Pragma("unroll") for (int nj = 0; nj < 4; ++nj)                      \
            acc[mi][nj] = __builtin_amdgcn_mfma_i32_16x16x64_i8(              \
                a[S][mi], b[S][nj], acc[mi][nj], 0, 0, 0);                    \
    __builtin_amdgcn_s_setprio(0);                                            \
    SB;                                                                       \
    LOAD_A_LO(((T) + 2) & (NT - 1), S); /* a[S][0..3] free now */             \
    SB;                                                                       \
    __builtin_amdgcn_s_setprio(1);                                            \
    _Pragma("unroll") for (int mi = 4; mi < 8; ++mi)                          \
        _Pragma("unroll") for (int nj = 0; nj < 4; ++nj)                      \
            acc[mi][nj] = __builtin_amdgcn_mfma_i32_16x16x64_i8(              \
                a[S][mi], b[S][nj], acc[mi][nj], 0, 0, 0);                    \
    __builtin_amdgcn_s_setprio(0);                                            \
    SB;                                                                       \
    LOAD_A_HI(((T) + 2) & (NT - 1), S); /* a[S][4..7], b[S] free now */       \
    LOAD_B(((T) + 2) & (NT - 1), S);                                          \
    SB;                                                                       \
  }

  // prologue: fill both slots (24 loads outstanding)
  LOAD_A_LO(0, 0);
  LOAD_A_HI(0, 0);
  LOAD_B(0, 0);
  LOAD_A_LO(1, 1);
  LOAD_A_HI(1, 1);
  LOAD_B(1, 1);

  for (int kt = 0; kt < NT; kt += 2) {
    BODY(kt, 0);
    BODY(kt + 1, 1);
  }
  // drain wrap-around prefetches so late writebacks can't clobber reused regs
  asm volatile("s_waitcnt vmcnt(0)" ::: "memory");
  SB;

  // epilogue: dequant + bias -> bf16-round -> f32 store
  // 16x16 C/D: col = lane&15, row = (lane>>4)*4 + reg
#pragma unroll
  for (int nj = 0; nj < 4; ++nj) {
    const int col_l = wc * 64 + nj * 16 + fr;
    const float wsv = wsc[rowB0 + col_l];
    const float bv = bias[rowB0 + col_l];
#pragma unroll
    for (int mi = 0; mi < 8; ++mi) {
#pragma unroll
      for (int r = 0; r < 4; ++r) {
        const size_t row = rowA0 + wr * 128 + mi * 16 + kg * 4 + r;
        const float f = (float)acc[mi][nj][r] * xs[row] * wsv + bv;
        C[row * GN + rowB0 + col_l] = __bfloat162float(__float2bfloat16(f));
      }
    }
  }
}

extern "C" void kernel_launch(void* const* d_in, const int* in_sizes, int n_in,
                              void* d_out, int out_size, void* d_ws, size_t ws_size,
                              hipStream_t stream) {
  const int M = GM, K = GK, N = GN;
  const float* x = (const float*)d_in[0];
  const int* W32 = (const int*)d_in[1];  // harness pushes integer inputs as int32
  const float* wsc = (const float*)d_in[2];
  const float* bias = (const float*)d_in[3];
  float* out = (float*)d_out;  // reference output dtype is float32 (bf16-rounded)

  // workspace layout: xs (16KB) | Xq2 (16MB packed) | Wt2 (64MB packed)
  float* xs = (float*)d_ws;
  int8_t* Xq2 = (int8_t*)d_ws + 16384;
  int8_t* Wt2 = (int8_t*)d_ws + 16384 + (size_t)M * K;

  transpose_pack<<<dim3(N / 64, K / 64), 256, 0, stream>>>(W32, Wt2, K, N);
  quant_rows<<<M, 256, 0, stream>>>(x, Xq2, xs, K);
  gemm_i8<<<dim3((M / BM) * (N / BN)), 512, 0, stream>>>(Xq2, Wt2, xs, wsc, bias,
                                                         out);
}

// Round 13
// 431.846 us; speedup vs baseline: 1.0899x; 1.0899x over previous
//
#include <hip/hip_runtime.h>
#include <hip/hip_bf16.h>
#include <stdint.h>

typedef int v4i __attribute__((ext_vector_type(4)));

#define GM 4096
#define GN 16384
#define GK 4096
#define BM 256
#define BN 256
#define BK 64         // i8 bytes per K-step
#define NT (GK / BK)  // 64 K-tiles

__device__ __forceinline__ void gload16(const void* g, void* l) {
  __builtin_amdgcn_global_load_lds(
      (const __attribute__((address_space(1))) void*)g,
      (__attribute__((address_space(3))) void*)l, 16, 0, 0);
}

// ---------------- per-row dynamic quantization -> fragment-ordered Xq2 ----------------
// Xq2[tm][kt][f][lane][16B]: lane l holds row tm*256 + f*16 + (l&15),
// k = kt*64 + (l>>4)*16 .. +16.
__global__ __launch_bounds__(256) void quant_rows(
    const float* __restrict__ x, int8_t* __restrict__ xq2,
    float* __restrict__ xs, int K) {
  const int row = blockIdx.x;
  const int t = threadIdx.x;
  const float4* src = (const float4*)(x + (size_t)row * K) + t * 4;
  float4 v[4];
  float m = 0.f;
#pragma unroll
  for (int i = 0; i < 4; ++i) {
    v[i] = src[i];
    m = fmaxf(m, fmaxf(fmaxf(fabsf(v[i].x), fabsf(v[i].y)),
                       fmaxf(fabsf(v[i].z), fabsf(v[i].w))));
  }
#pragma unroll
  for (int off = 1; off < 64; off <<= 1)
    m = fmaxf(m, __shfl_xor(m, off, 64));
  __shared__ float wmax[4];
  if ((t & 63) == 0) wmax[t >> 6] = m;
  __syncthreads();
  const float gm = fmaxf(fmaxf(wmax[0], wmax[1]), fmaxf(wmax[2], wmax[3]));
  const float scale = (gm + 1e-5f) / 127.0f;  // == ref x_scales
  if (t == 0) xs[row] = scale;
  unsigned packed[4];
#pragma unroll
  for (int i = 0; i < 4; ++i) {
    float fv[4] = {v[i].x, v[i].y, v[i].z, v[i].w};
    unsigned p = 0;
#pragma unroll
    for (int j = 0; j < 4; ++j) {
      int q = (int)rintf(fv[j] / scale);  // RNE, matches np.round
      q = max(-128, min(127, q));
      p |= (unsigned)(q & 0xff) << (8 * j);
    }
    packed[i] = p;
  }
  // thread t owns the 16B chunk at k = t*16: kt = t>>2, kg = t&3
  const int tm = row >> 8, f = (row >> 4) & 15, fr = row & 15;
  const int kt = t >> 2, kg = t & 3;
  int8_t* dst =
      xq2 + ((((size_t)(tm * 64 + kt) * 16 + f) * 64) + fr + 16 * kg) * 16;
  *(int4*)dst =
      make_int4((int)packed[0], (int)packed[1], (int)packed[2], (int)packed[3]);
}

// ------- W int32 [K][N] -> Wt2 int8 in MFMA-fragment order -------
// Wt2[tn][kt][f][lane][16B]: lane l holds col n = tn*256 + f*16 + (l&15),
// k = kt*64 + (l>>4)*16 .. +16.  One fragment = 1 KB contiguous.
__global__ __launch_bounds__(256) void transpose_pack(
    const int* __restrict__ W32, int8_t* __restrict__ Wt2, int K, int N) {
  __shared__ __align__(16) int8_t tile[64][80];
  const int t = threadIdx.x;
  const int n0 = blockIdx.x * 64;
  const int k0 = blockIdx.y * 64;
  const int ln = t & 63;
  const int wv = t >> 6;
#pragma unroll
  for (int it = 0; it < 16; ++it) {
    const int kk = wv * 16 + it;
    tile[ln][kk] = (int8_t)W32[(size_t)(k0 + kk) * N + n0 + ln];
  }
  __syncthreads();
  const int lane = ln;
  const int4 v = *(const int4*)&tile[wv * 16 + (lane & 15)][(lane >> 4) * 16];
  const int tn = n0 >> 8;
  const int kt = k0 >> 6;
  const int f = ((n0 >> 4) & 15) + wv;
  *(int4*)(Wt2 + (((size_t)(tn * 64 + kt) * 16 + f) * 64 + lane) * 16) = v;
}

// ---- int8 GEMM: A via fragment-ordered LDS ring (linear stage, conflict-free ----
// ---- reads), B direct global->VGPR; depth-3 never-drain; one barrier/tile.   ----
__global__ __launch_bounds__(512, 2) void gemm_i8(
    const int8_t* __restrict__ Xq2, const int8_t* __restrict__ Wt2,
    const float* __restrict__ xs, const float* __restrict__ wsc,
    const float* __restrict__ bias, float* __restrict__ C) {
  __shared__ __align__(16) int8_t lA[4][16384];  // 64 KB: [slot][f][lane][16B]

  const int t = threadIdx.x;
  const int lane = t & 63;
  const int w = t >> 6;
  const int wr = w >> 2;  // 0..1 (M half: 128 rows)
  const int wc = w & 3;   // 0..3 (N quarter: 64 cols)
  const int fr = lane & 15;
  const int kg = lane >> 4;

  // bijective XCD swizzle: 1024 blocks = 8 XCD x (16 M x 8 N) rectangles
  const int bid = blockIdx.x;
  const int xcd = bid & 7;
  const int q = bid >> 3;
  const int tm = q & 15;
  const int tn = xcd * 8 + (q >> 4);
  const size_t rowA0 = (size_t)tm * BM;
  const size_t rowB0 = (size_t)tn * BN;

  // A tile (16 KB, linear in fragment order); wave w stages frags 2w, 2w+1.
  // global_load_lds: LDS dest = wave-uniform base + lane*16 (HW);
  // global SOURCE is per-lane -> MUST include lane*16 (R12 bug was omitting it).
  const int8_t* aqB = Xq2 + (size_t)tm * 1048576 + w * 2048 + (size_t)lane * 16;
  const int dstO = w * 2048;  // wave-uniform LDS base

#define STAGE(KT, SLOT)                                           \
  {                                                               \
    const int8_t* p = aqB + (size_t)(KT)*16384;                   \
    gload16(p, &lA[(SLOT)][0] + dstO);                            \
    gload16(p + 1024, &lA[(SLOT)][0] + dstO + 1024);              \
  }

  // B fragment base for this wave: f = wc*4 + nj
  const int8_t* bq = Wt2 + (size_t)tn * 1048576 + wc * 4096 + (size_t)lane * 16;

  v4i acc[8][4] = {};
  v4i areg[8], breg[4][4];  // breg[slot][nj]

#define LD(dst, ptr)                                        \
  asm volatile("global_load_dwordx4 %0, %1, off"            \
               : "=v"(dst)                                  \
               : "v"(ptr)                                   \
               : "memory")

#define LOADB(KT, S)                                        \
  {                                                         \
    const int8_t* bp = bq + (size_t)(KT)*16384;             \
    LD(breg[S][0], bp);                                     \
    LD(breg[S][1], bp + 1024);                              \
    LD(breg[S][2], bp + 2048);                              \
    LD(breg[S][3], bp + 3072);                              \
  }

  // A fragment read: frag = wr*8 + mi, lane-linear -> conflict-free
#define RD_A(MI, SLOT)                                                     \
  areg[MI] = *(const v4i*)&lA[(SLOT)][(wr * 8 + (MI)) * 1024 + lane * 16];

#define SB __builtin_amdgcn_sched_barrier(0)

#define BODY(T, SLOT)                                                         \
  {                                                                           \
    /* gate: batch T landed (T+1,T+2 = 12 loads still flying) */              \
    asm volatile("s_waitcnt vmcnt(12)" ::: "memory");                         \
    __builtin_amdgcn_s_barrier(); /* A(T) resident CU-wide; ring slot free */ \
    SB;                                                                       \
    STAGE(((T) + 3) & (NT - 1), ((SLOT) + 3) & 3);                            \
    LOADB(((T) + 3) & (NT - 1), ((SLOT) + 3) & 3);                            \
    SB;                                                                       \
    RD_A(0, SLOT); RD_A(1, SLOT); RD_A(2, SLOT); RD_A(3, SLOT);               \
    SB;                                                                       \
    RD_A(4, SLOT); RD_A(5, SLOT); RD_A(6, SLOT); RD_A(7, SLOT);               \
    SB;                                                                       \
    asm volatile("s_waitcnt lgkmcnt(4)" ::: "memory"); /* A0-3 ready */       \
    SB;                                                                       \
    __builtin_amdgcn_s_setprio(1);                                            \
    _Pragma("unroll") for (int mi = 0; mi < 4; ++mi)                          \
        _Pragma("unroll") for (int nj = 0; nj < 4; ++nj)                      \
            acc[mi][nj] = __builtin_amdgcn_mfma_i32_16x16x64_i8(              \
                areg[mi], breg[SLOT][nj], acc[mi][nj], 0, 0, 0);              \
    __builtin_amdgcn_s_setprio(0);                                            \
    asm volatile("s_waitcnt lgkmcnt(0)" ::: "memory"); /* A4-7 ready */       \
    SB;                                                                       \
    __builtin_amdgcn_s_setprio(1);                                            \
    _Pragma("unroll") for (int mi = 4; mi < 8; ++mi)                          \
        _Pragma("unroll") for (int nj = 0; nj < 4; ++nj)                      \
            acc[mi][nj] = __builtin_amdgcn_mfma_i32_16x16x64_i8(              \
                areg[mi], breg[SLOT][nj], acc[mi][nj], 0, 0, 0);              \
    __builtin_amdgcn_s_setprio(0);                                            \
  }

  // prologue: issue batches 0,1,2 (A-stage + B-loads each; 18 loads out)
  STAGE(0, 0);
  LOADB(0, 0);
  STAGE(1, 1);
  LOADB(1, 1);
  STAGE(2, 2);
  LOADB(2, 2);

  for (int kt = 0; kt < NT; kt += 4) {
    BODY(kt, 0);
    BODY(kt + 1, 1);
    BODY(kt + 2, 2);
    BODY(kt + 3, 3);
  }
  // drain wrap-around prefetches so late writebacks can't clobber reused regs
  asm volatile("s_waitcnt vmcnt(0) lgkmcnt(0)" ::: "memory");
  SB;

  // epilogue: dequant + bias -> bf16-round -> f32 store
  // 16x16 C/D: col = lane&15, row = (lane>>4)*4 + reg
#pragma unroll
  for (int nj = 0; nj < 4; ++nj) {
    const int col_l = wc * 64 + nj * 16 + fr;
    const float wsv = wsc[rowB0 + col_l];
    const float bv = bias[rowB0 + col_l];
#pragma unroll
    for (int mi = 0; mi < 8; ++mi) {
#pragma unroll
      for (int r = 0; r < 4; ++r) {
        const size_t row = rowA0 + wr * 128 + mi * 16 + kg * 4 + r;
        const float f = (float)acc[mi][nj][r] * xs[row] * wsv + bv;
        C[row * GN + rowB0 + col_l] = __bfloat162float(__float2bfloat16(f));
      }
    }
  }
}

extern "C" void kernel_launch(void* const* d_in, const int* in_sizes, int n_in,
                              void* d_out, int out_size, void* d_ws, size_t ws_size,
                              hipStream_t stream) {
  const int M = GM, K = GK, N = GN;
  const float* x = (const float*)d_in[0];
  const int* W32 = (const int*)d_in[1];  // harness pushes integer inputs as int32
  const float* wsc = (const float*)d_in[2];
  const float* bias = (const float*)d_in[3];
  float* out = (float*)d_out;  // reference output dtype is float32 (bf16-rounded)

  // workspace layout: xs (16KB) | Xq2 (16MB packed) | Wt2 (64MB packed)
  float* xs = (float*)d_ws;
  int8_t* Xq2 = (int8_t*)d_ws + 16384;
  int8_t* Wt2 = (int8_t*)d_ws + 16384 + (size_t)M * K;

  transpose_pack<<<dim3(N / 64, K / 64), 256, 0, stream>>>(W32, Wt2, K, N);
  quant_rows<<<M, 256, 0, stream>>>(x, Xq2, xs, K);
  gemm_i8<<<dim3((M / BM) * (N / BN)), 512, 0, stream>>>(Xq2, Wt2, xs, wsc, bias,
                                                         out);
}